// Round 5
// baseline (130.578 us; speedup 1.0000x reference)
//
#include <hip/hip_runtime.h>
#include <hip/hip_bf16.h>

// Problem: X[64][1024][128] fp32. out = mean_{b,s,t} (cos(x_bs, x_bt) - 1)^2
// Identity: sum_{s,t}(S_st-1)^2 = ||G||_F^2 - 2*||v||^2 + S^2, where
//   G = Xn^T Xn (128x128 feature Gram per batch), v = sum_s xn_s.
// Numerator precision budget: 0.02*2^26 ~ 1.35e6 vs value ~5e5 -> bf16 Gram
// via MFMA is safe by ~3 orders of magnitude.
//
// ROUND-5: k1 was scalar-FMA bound (~45 us). Move Gram to matrix pipe:
// bf16 LDS staging (transposed, stride-72 rows: 16B-aligned ds_read_b128,
// ~4-way banks) + v_mfma_f32_32x32x16_bf16. KSPLIT 8->4 halves gpart traffic
// (16 MB). All-private partials -> no atomics -> k0 dropped (3 kernels).

#define BATCH  64
#define SEQ    1024
#define DIM    128
#define KSPLIT 4
#define ROWS_PER_WG (SEQ / KSPLIT)    // 256 rows per wg
#define SCH    64                     // rows (s) staged per chunk
#define NCH    (ROWS_PER_WG / SCH)    // 4 chunks
#define SROW   72                     // LDS row stride in bf16 (144 B: 16B-aligned)
#define GSZ    (DIM * DIM)            // 16384 floats per partial Gram

// ws layout (floats): [0, 256*16384) gpart (16 MB);
//   then vpart[256][128] (128 KB); then res[256] (1 KB). Total ~16.2 MB.
#define GP_OFF   0
#define VP_OFF   ((size_t)(BATCH * KSPLIT) * GSZ)
#define RES_OFF  (VP_OFF + (size_t)(BATCH * KSPLIT) * DIM)

typedef short short8 __attribute__((ext_vector_type(8)));    // 8 bf16 = 4 VGPR
typedef float floatx16 __attribute__((ext_vector_type(16))); // 32x32 acc

__device__ __forceinline__ short f2bf(float x) {
    unsigned u = __builtin_bit_cast(unsigned, x);
    return (short)((u + 0x7FFFu + ((u >> 16) & 1u)) >> 16);   // RNE
}

// ---- k1: wg = (batch b, k-split ks): normalize 256 rows, bf16-stage
//      transposed in LDS, MFMA partial Gram, private v-partials. ----
__global__ __launch_bounds__(256, 1)
void k1_gram(const float* __restrict__ X, float* __restrict__ gpart,
             float* __restrict__ vpart) {
    __shared__ __align__(16) short ldsT[2][DIM * SROW];  // 2 x 18 KB

    const int t    = threadIdx.x;
    const int wg   = blockIdx.x;
    const int b    = wg >> 2;
    const int ksp  = wg & 3;
    const int lane = t & 63;
    const int w    = t >> 6;          // wave 0..3 -> G row band 32w..32w+31
    const int m    = lane & 31;
    const int ko   = (lane >> 5) * 8; // k-offset within 16-step: 0 or 8

    const int sl   = t >> 2;          // staging row-in-chunk 0..63
    const int qb   = t & 3;           // staging phase 0..3

    const float* Xbase = X + ((size_t)b * SEQ + (size_t)ksp * ROWS_PER_WG) * DIM;

    floatx16 acc[4];
#pragma unroll
    for (int f = 0; f < 4; ++f)
#pragma unroll
        for (int r = 0; r < 16; ++r) acc[f][r] = 0.0f;

    float vreg[32];                    // this thread's 32 features' v-partial
#pragma unroll
    for (int k = 0; k < 32; ++k) vreg[k] = 0.0f;

    float4 g4[8];

    // ---- stage chunk 0 into buffer 0 ----
    {
        const float4* rowp = (const float4*)(Xbase + (size_t)sl * DIM);
#pragma unroll
        for (int k = 0; k < 8; ++k) g4[k] = rowp[qb + 4 * k];
        float ssq = 0.0f;
#pragma unroll
        for (int k = 0; k < 8; ++k)
            ssq += g4[k].x * g4[k].x + g4[k].y * g4[k].y +
                   g4[k].z * g4[k].z + g4[k].w * g4[k].w;
        ssq += __shfl_xor(ssq, 1);
        ssq += __shfl_xor(ssq, 2);
        float inv = rsqrtf(fmaxf(ssq, 1e-24f));
#pragma unroll
        for (int k = 0; k < 8; ++k) {
            const float vx[4] = {g4[k].x * inv, g4[k].y * inv,
                                 g4[k].z * inv, g4[k].w * inv};
#pragma unroll
            for (int c = 0; c < 4; ++c) {
                const int f = 4 * qb + 16 * k + c;     // feature index
                vreg[k * 4 + c] += vx[c];
                ldsT[0][f * SROW + sl] = f2bf(vx[c]);
            }
        }
    }
    __syncthreads();

    for (int c = 0; c < NCH; ++c) {
        const int cur = c & 1;
        // prefetch next chunk's rows into registers
        if (c + 1 < NCH) {
            const float4* rowp =
                (const float4*)(Xbase + (size_t)((c + 1) * SCH + sl) * DIM);
#pragma unroll
            for (int k = 0; k < 8; ++k) g4[k] = rowp[qb + 4 * k];
        }
        // MFMA over this chunk: 4 K-steps of 16
        const short* buf = ldsT[cur];
#pragma unroll
        for (int ks = 0; ks < 4; ++ks) {
            const int s0 = ks * 16 + ko;
            short8 frag[4];
#pragma unroll
            for (int f = 0; f < 4; ++f)
                frag[f] = *(const short8*)&buf[(32 * f + m) * SROW + s0];
#pragma unroll
            for (int f = 0; f < 4; ++f)
                acc[f] = __builtin_amdgcn_mfma_f32_32x32x16_bf16(
                    frag[w], frag[f], acc[f], 0, 0, 0);
        }
        // normalize + stage next chunk into the other buffer
        if (c + 1 < NCH) {
            float ssq = 0.0f;
#pragma unroll
            for (int k = 0; k < 8; ++k)
                ssq += g4[k].x * g4[k].x + g4[k].y * g4[k].y +
                       g4[k].z * g4[k].z + g4[k].w * g4[k].w;
            ssq += __shfl_xor(ssq, 1);
            ssq += __shfl_xor(ssq, 2);
            float inv = rsqrtf(fmaxf(ssq, 1e-24f));
            short* nbuf = ldsT[1 - cur];
#pragma unroll
            for (int k = 0; k < 8; ++k) {
                const float vx[4] = {g4[k].x * inv, g4[k].y * inv,
                                     g4[k].z * inv, g4[k].w * inv};
#pragma unroll
                for (int cc = 0; cc < 4; ++cc) {
                    const int f = 4 * qb + 16 * k + cc;
                    vreg[k * 4 + cc] += vx[cc];
                    nbuf[f * SROW + sl] = f2bf(vx[cc]);
                }
            }
        }
        __syncthreads();
    }

    // ---- epilogue: store partial Gram (C/D layout: col=lane&31,
    //      row=(reg&3)+8*(reg>>2)+4*(lane>>5)) ----
    float* gp = gpart + (size_t)wg * GSZ;
#pragma unroll
    for (int f = 0; f < 4; ++f) {
#pragma unroll
        for (int r = 0; r < 16; ++r) {
            const int row = (r & 3) + 8 * (r >> 2) + 4 * (lane >> 5);
            gp[(size_t)(32 * w + row) * DIM + 32 * f + (lane & 31)] = acc[f][r];
        }
    }

    // ---- v-partial: block-reduce vreg via LDS scratch (reuse ldsT) ----
    __syncthreads();
    float* scratch = (float*)ldsT;      // 256*32 floats = 32 KB <= 36 KB
#pragma unroll
    for (int k = 0; k < 32; ++k) scratch[t * 32 + k] = vreg[k];
    __syncthreads();
    if (t < DIM) {
        // feature f owned by threads with t&3 == (f>>2)&3 at vreg idx
        // (f>>4)*4 + (f&3)
        const int tsel = (t >> 2) & 3;
        const int idx  = (t >> 4) * 4 + (t & 3);
        float v = 0.0f;
        for (int g = 0; g < 64; ++g)
            v += scratch[(g * 4 + tsel) * 32 + idx];
        vpart[(size_t)wg * DIM + t] = v;
    }
}

// ---- k2: wg = (batch b, quarter q): sum 4 partial-Gram quarters,
//      accumulate ||G||_F^2 (and -2||v||^2 on q==0) -> res[wg]. ----
__global__ __launch_bounds__(256, 2)
void k2_reduce(const float* __restrict__ gpart, const float* __restrict__ vpart,
               float* __restrict__ res) {
    const int t = threadIdx.x;
    const int b = blockIdx.x >> 2;
    const int q = blockIdx.x & 3;
    const float4* gb = (const float4*)(gpart + (size_t)b * KSPLIT * GSZ);

    float sG = 0.0f;
#pragma unroll
    for (int it = 0; it < 4; ++it) {
        const int e4 = q * 1024 + it * 256 + t;
        float4 s = gb[e4];
#pragma unroll
        for (int slot = 1; slot < KSPLIT; ++slot) {
            float4 p = gb[(size_t)slot * (GSZ / 4) + e4];
            s.x += p.x; s.y += p.y; s.z += p.z; s.w += p.w;
        }
        sG += s.x * s.x + s.y * s.y + s.z * s.z + s.w * s.w;
    }
    float sV = 0.0f;
    if (q == 0 && t < DIM) {
        float vv = 0.0f;
#pragma unroll
        for (int slot = 0; slot < KSPLIT; ++slot)
            vv += vpart[(size_t)(b * KSPLIT + slot) * DIM + t];
        sV = vv * vv;
    }
#pragma unroll
    for (int msk = 1; msk < 64; msk <<= 1) {
        sG += __shfl_xor(sG, msk);
        sV += __shfl_xor(sV, msk);
    }
    __shared__ float wq[8];
    if ((t & 63) == 0) { wq[t >> 6] = sG; wq[4 + (t >> 6)] = sV; }
    __syncthreads();
    if (t == 0)
        res[blockIdx.x] = (wq[0] + wq[1] + wq[2] + wq[3]) -
                          2.0f * (wq[4] + wq[5] + wq[6] + wq[7]);
}

// ---- k3: out = sum(res)/ (B*S^2) + 1 ----
__global__ __launch_bounds__(256)
void k3_final(const float* __restrict__ res, float* __restrict__ out) {
    const int t = threadIdx.x;
    float s = res[t];
#pragma unroll
    for (int msk = 1; msk < 64; msk <<= 1) s += __shfl_xor(s, msk);
    __shared__ float wq[4];
    if ((t & 63) == 0) wq[t >> 6] = s;
    __syncthreads();
    if (t == 0)
        out[0] = (wq[0] + wq[1] + wq[2] + wq[3]) * (1.0f / 67108864.0f) + 1.0f;
}

extern "C" void kernel_launch(void* const* d_in, const int* in_sizes, int n_in,
                              void* d_out, int out_size, void* d_ws, size_t ws_size,
                              hipStream_t stream) {
    const float* X = (const float*)d_in[0];
    float* ws = (float*)d_ws;          // needs ~16.2 MB (proven available)
    float* gpart = ws + GP_OFF;
    float* vpart = ws + VP_OFF;
    float* res   = ws + RES_OFF;

    k1_gram<<<BATCH * KSPLIT, 256, 0, stream>>>(X, gpart, vpart);
    k2_reduce<<<BATCH * 4, 256, 0, stream>>>(gpart, vpart, res);
    k3_final<<<1, 256, 0, stream>>>(res, (float*)d_out);
}

// Round 7
// 104.838 us; speedup vs baseline: 1.2455x; 1.2455x over previous
//
#include <hip/hip_runtime.h>
#include <hip/hip_bf16.h>

// Problem: X[64][1024][128] fp32. out = mean_{b,s,t} (cos(x_bs, x_bt) - 1)^2
// Identity: sum_{s,t}(S_st-1)^2 = ||G||_F^2 - 2*||v||^2 + S^2,
//   G = Xn^T Xn (128x128 per batch), v = sum_s xn_s. 2.15 GFLOP, no SxS.
// Precision: numerator slack 0.02*2^26 ~ 1.35e6 vs bf16-Gram error ~ tens.
//
// ROUND-7: round-6 NaN root-caused to kB staging: LDS write used h*16 while
// the global read used h*32 -> words 16..31 double-written, words 48..63 of
// every row UNINITIALIZED -> NaN into MFMA. One-line fix (h*32). Everything
// else unchanged.

#define BATCH 64
#define SEQ   1024
#define DIM   128

typedef short short8  __attribute__((ext_vector_type(8)));
typedef float floatx4 __attribute__((ext_vector_type(4)));

__device__ __forceinline__ unsigned bf16rne(float x) {
    unsigned u = __builtin_bit_cast(unsigned, x);
    return (u + 0x7FFFu + ((u >> 16) & 1u)) >> 16;
}

// ws layout (bytes): [0,16MB) XnT bf16 [64][128][1024];
//   [16MB,+512KB) vpartA[512][256]; then res[512]; then res2[64].
#define XNT_B  0
#define VP_B   16777216
#define RES_B  (VP_B + 512 * 256 * 4)
#define RES2_B (RES_B + 512 * 4)

// ---- kA: wg=(b, sblk of 128 s). Normalize rows, transpose via LDS,
//      store bf16 XnT + per-thread v partials. ----
__global__ __launch_bounds__(256, 2)
void kA_norm_t(const float* __restrict__ X, unsigned* __restrict__ XnT,
               float* __restrict__ vpartA) {
    __shared__ __align__(16) float lds[64][132];   // 33.8 KB, +4 pad
    const int t    = threadIdx.x;
    const int wg   = blockIdx.x;           // b*8 + sblk
    const int b    = wg >> 3, sblk = wg & 7;
    const int sl   = t >> 2, q = t & 3;    // staging: 4 thr/row, 32 f each
    const int f    = t & 127, sh = t >> 7; // transpose: feature f, s-half

    // load both 64-row chunks up front (independent; hides HBM latency)
    float4 g[2][8];
#pragma unroll
    for (int c = 0; c < 2; ++c) {
        const float4* rp = (const float4*)(
            X + ((size_t)(b * SEQ + sblk * 128 + c * 64 + sl) * DIM + q * 32));
#pragma unroll
        for (int k = 0; k < 8; ++k) g[c][k] = rp[k];
    }

    float vacc = 0.0f;
#pragma unroll
    for (int c = 0; c < 2; ++c) {
        float ssq = 0.0f;
#pragma unroll
        for (int k = 0; k < 8; ++k)
            ssq += g[c][k].x * g[c][k].x + g[c][k].y * g[c][k].y +
                   g[c][k].z * g[c][k].z + g[c][k].w * g[c][k].w;
        ssq += __shfl_xor(ssq, 1);
        ssq += __shfl_xor(ssq, 2);
        const float inv = rsqrtf(fmaxf(ssq, 1e-24f));

        if (c) __syncthreads();            // chunk-0 readers done
#pragma unroll
        for (int k = 0; k < 8; ++k) {
            float4 n;
            n.x = g[c][k].x * inv; n.y = g[c][k].y * inv;
            n.z = g[c][k].z * inv; n.w = g[c][k].w * inv;
            *(float4*)&lds[sl][q * 32 + k * 4] = n;   // b128, natural layout
        }
        __syncthreads();

        // transposed read: column f, 32 consecutive s (2 lanes/bank: free)
        float v[32];
#pragma unroll
        for (int j = 0; j < 32; ++j) {
            v[j] = lds[sh * 32 + j][f];
            vacc += v[j];
        }
        unsigned pk[16];
#pragma unroll
        for (int p = 0; p < 16; ++p)
            pk[p] = bf16rne(v[2 * p]) | (bf16rne(v[2 * p + 1]) << 16);
        // 64 B contiguous per lane, 64 B sector-aligned
        unsigned* op = XnT + (((size_t)(b * DIM + f)) << 9) +
                       (sblk * 64 + c * 32 + sh * 16);
#pragma unroll
        for (int k = 0; k < 4; ++k)
            ((uint4*)op)[k] = make_uint4(pk[4 * k], pk[4 * k + 1],
                                         pk[4 * k + 2], pk[4 * k + 3]);
    }
    vpartA[(size_t)wg * 256 + t] = vacc;   // t = sh*128 + f
}

// ---- kB: wg=(b, band of 16 G-rows), full K=1024. Stage 128f x 128s bf16
//      per k-chunk, 2 MFMAs/wave/k-step, square-reduce locally. ----
#define SROWW 68    // LDS row stride in words (272 B): 16B-aligned b128
__global__ __launch_bounds__(256, 2)
void kB_gram(const unsigned* __restrict__ XnT, float* __restrict__ res) {
    __shared__ __align__(16) unsigned ldsB[DIM * SROWW];  // 34.8 KB
    __shared__ float wq[4];
    const int t    = threadIdx.x;
    const int b    = blockIdx.x >> 3, band = blockIdx.x & 7;
    const int lane = t & 63, w = t >> 6;
    const int l15  = lane & 15;
    const int koff = (lane >> 4) * 4;      // word offset: (lane>>4)*8 shorts
    const int fs   = t >> 1, h = t & 1;    // staging: 2 thr/row, 32 words each

    const unsigned* gsrc =
        XnT + (((size_t)(b * DIM + fs)) << 9) + h * 32;

    floatx4 acc0 = {0.f, 0.f, 0.f, 0.f}, acc1 = {0.f, 0.f, 0.f, 0.f};

    for (int kc = 0; kc < 8; ++kc) {
        // stage 128 rows x 128 s (64 uints/row); h covers words h*32..h*32+31
        const uint4* gp = (const uint4*)(gsrc + kc * 64);
        unsigned* lp = ldsB + fs * SROWW + h * 32;   // ROUND-7 FIX (was h*16)
#pragma unroll
        for (int j = 0; j < 8; ++j) ((uint4*)lp)[j] = gp[j];
        __syncthreads();

#pragma unroll
        for (int ks = 0; ks < 4; ++ks) {
            const int sw = ks * 16 + koff;
            short8 a  = *(const short8*)(ldsB + (band * 16 + l15) * SROWW + sw);
            short8 b0 = *(const short8*)(ldsB + ((2 * w) * 16 + l15) * SROWW + sw);
            short8 b1 = *(const short8*)(ldsB + ((2 * w + 1) * 16 + l15) * SROWW + sw);
            acc0 = __builtin_amdgcn_mfma_f32_16x16x32_bf16(a, b0, acc0, 0, 0, 0);
            acc1 = __builtin_amdgcn_mfma_f32_16x16x32_bf16(a, b1, acc1, 0, 0, 0);
        }
        __syncthreads();
    }

    float s = acc0[0] * acc0[0] + acc0[1] * acc0[1] +
              acc0[2] * acc0[2] + acc0[3] * acc0[3] +
              acc1[0] * acc1[0] + acc1[1] * acc1[1] +
              acc1[2] * acc1[2] + acc1[3] * acc1[3];
#pragma unroll
    for (int m = 1; m < 64; m <<= 1) s += __shfl_xor(s, m);
    if (lane == 0) wq[w] = s;
    __syncthreads();
    if (t == 0) res[blockIdx.x] = wq[0] + wq[1] + wq[2] + wq[3];
}

// ---- kV: per batch, ||v_b||^2 from vpartA ----
__global__ __launch_bounds__(128)
void kV_vnorm(const float* __restrict__ vpartA, float* __restrict__ res2) {
    const int b = blockIdx.x, t = threadIdx.x;   // t = feature
    float vv = 0.0f;
#pragma unroll
    for (int sblk = 0; sblk < 8; ++sblk) {
        const float* p = vpartA + (size_t)(b * 8 + sblk) * 256;
        vv += p[t] + p[t + 128];
    }
    float v2 = vv * vv;
#pragma unroll
    for (int m = 1; m < 64; m <<= 1) v2 += __shfl_xor(v2, m);
    __shared__ float s2[2];
    if ((t & 63) == 0) s2[t >> 6] = v2;
    __syncthreads();
    if (t == 0) res2[b] = s2[0] + s2[1];
}

// ---- kF: out = (sum(res) - 2*sum(res2)) / (B*S^2) + 1 ----
__global__ __launch_bounds__(256)
void kF_final(const float* __restrict__ res, const float* __restrict__ res2,
              float* __restrict__ out) {
    const int t = threadIdx.x;
    float s = res[t] + res[t + 256];
    if (t < 64) s -= 2.0f * res2[t];
#pragma unroll
    for (int m = 1; m < 64; m <<= 1) s += __shfl_xor(s, m);
    __shared__ float wq[4];
    if ((t & 63) == 0) wq[t >> 6] = s;
    __syncthreads();
    if (t == 0)
        out[0] = (wq[0] + wq[1] + wq[2] + wq[3]) * (1.0f / 67108864.0f) + 1.0f;
}

extern "C" void kernel_launch(void* const* d_in, const int* in_sizes, int n_in,
                              void* d_out, int out_size, void* d_ws, size_t ws_size,
                              hipStream_t stream) {
    const float* X = (const float*)d_in[0];
    char* ws = (char*)d_ws;                 // needs ~17.3 MB
    unsigned* XnT  = (unsigned*)(ws + XNT_B);
    float* vpartA  = (float*)(ws + VP_B);
    float* res     = (float*)(ws + RES_B);
    float* res2    = (float*)(ws + RES2_B);

    kA_norm_t<<<512, 256, 0, stream>>>(X, XnT, vpartA);
    kB_gram<<<512, 256, 0, stream>>>(XnT, res);
    kV_vnorm<<<64, 128, 0, stream>>>(vpartA, res2);
    kF_final<<<1, 256, 0, stream>>>(res, res2, (float*)d_out);
}

// Round 8
// 103.021 us; speedup vs baseline: 1.2675x; 1.0176x over previous
//
#include <hip/hip_runtime.h>
#include <hip/hip_bf16.h>

// Problem: X[64][1024][128] fp32. out = mean_{b,s,t} (cos(x_bs, x_bt) - 1)^2
// Identity: sum_{s,t}(S_st-1)^2 = ||G||_F^2 - 2*||v||^2 + S^2,
//   G = Xn^T Xn (128x128 per batch), v = sum_s xn_s. 2.15 GFLOP, no SxS.
// Precision: numerator slack 0.02*2^26 ~ 1.35e6 vs bf16-Gram error ~ tens.
//
// ROUND-8: round-7 passed (104.8 us); kB (~25-35 us est.) was cross-XCD
// L3-bound: blockIdx=b*8+band spread one batch's 8 band-wgs over 8 XCDs.
// Changes: (1) XCD-pin swizzle wg=band*64+b -> batch b's bands all on XCD
// b%8, 2 MB/XCD working set fits L2; kA swizzled to match. (2) kB reads MFMA
// fragments DIRECTLY from global (each fragment = contiguous 16 B of an XnT
// row) -> no LDS, no barriers (was 16/wg). (3) kV folded into kB band-0 wgs
// -> 3 launches.

#define BATCH 64
#define SEQ   1024
#define DIM   128

typedef short short8  __attribute__((ext_vector_type(8)));
typedef float floatx4 __attribute__((ext_vector_type(4)));

__device__ __forceinline__ unsigned bf16rne(float x) {
    unsigned u = __builtin_bit_cast(unsigned, x);
    return (u + 0x7FFFu + ((u >> 16) & 1u)) >> 16;
}

// ws layout (bytes): [0,16MB) XnT bf16 [64][128][1024];
//   [16MB,+512KB) vpartA[512][256]; then res[512].
#define XNT_B  0
#define VP_B   16777216
#define RES_B  (VP_B + 512 * 256 * 4)

// ---- kA: wg decodes (sblk, b) XCD-pinned: b = wg&63 -> XCD b%8.
//      Normalize 128 rows, transpose via LDS, store bf16 XnT + v partials. ----
__global__ __launch_bounds__(256, 2)
void kA_norm_t(const float* __restrict__ X, unsigned* __restrict__ XnT,
               float* __restrict__ vpartA) {
    __shared__ __align__(16) float lds[64][132];   // 33.8 KB, +4 pad
    const int t    = threadIdx.x;
    const int wg   = blockIdx.x;           // sblk*64 + b  (XCD = b%8)
    const int b    = wg & 63, sblk = wg >> 6;
    const int sl   = t >> 2, q = t & 3;    // staging: 4 thr/row, 32 f each
    const int f    = t & 127, sh = t >> 7; // transpose: feature f, s-half

    // load both 64-row chunks up front (independent; hides HBM latency)
    float4 g[2][8];
#pragma unroll
    for (int c = 0; c < 2; ++c) {
        const float4* rp = (const float4*)(
            X + ((size_t)(b * SEQ + sblk * 128 + c * 64 + sl) * DIM + q * 32));
#pragma unroll
        for (int k = 0; k < 8; ++k) g[c][k] = rp[k];
    }

    float vacc = 0.0f;
#pragma unroll
    for (int c = 0; c < 2; ++c) {
        float ssq = 0.0f;
#pragma unroll
        for (int k = 0; k < 8; ++k)
            ssq += g[c][k].x * g[c][k].x + g[c][k].y * g[c][k].y +
                   g[c][k].z * g[c][k].z + g[c][k].w * g[c][k].w;
        ssq += __shfl_xor(ssq, 1);
        ssq += __shfl_xor(ssq, 2);
        const float inv = rsqrtf(fmaxf(ssq, 1e-24f));

        if (c) __syncthreads();            // chunk-0 readers done
#pragma unroll
        for (int k = 0; k < 8; ++k) {
            float4 n;
            n.x = g[c][k].x * inv; n.y = g[c][k].y * inv;
            n.z = g[c][k].z * inv; n.w = g[c][k].w * inv;
            *(float4*)&lds[sl][q * 32 + k * 4] = n;   // b128, natural layout
        }
        __syncthreads();

        // transposed read: column f, 32 consecutive s (2 lanes/bank: free)
        float v[32];
#pragma unroll
        for (int j = 0; j < 32; ++j) {
            v[j] = lds[sh * 32 + j][f];
            vacc += v[j];
        }
        unsigned pk[16];
#pragma unroll
        for (int p = 0; p < 16; ++p)
            pk[p] = bf16rne(v[2 * p]) | (bf16rne(v[2 * p + 1]) << 16);
        // 64 B contiguous per lane, 64 B sector-aligned
        unsigned* op = XnT + (((size_t)(b * DIM + f)) << 9) +
                       (sblk * 64 + c * 32 + sh * 16);
#pragma unroll
        for (int k = 0; k < 4; ++k)
            ((uint4*)op)[k] = make_uint4(pk[4 * k], pk[4 * k + 1],
                                         pk[4 * k + 2], pk[4 * k + 3]);
    }
    vpartA[(size_t)wg * 256 + t] = vacc;   // slice index = sblk*64+b = wg
}

// ---- kB: wg = band*64 + b (XCD-pinned to b%8). Full K=1024 Gram strip,
//      fragments loaded directly from global (L2-resident), no LDS/barriers.
//      band 0 additionally folds -2*||v_b||^2. ----
__global__ __launch_bounds__(256, 2)
void kB_gram(const unsigned* __restrict__ XnT, const float* __restrict__ vpartA,
             float* __restrict__ res) {
    const int t    = threadIdx.x;
    const int wg   = blockIdx.x;
    const int b    = wg & 63, band = wg >> 6;
    const int lane = t & 63, w = t >> 6;
    const int l15  = lane & 15;
    const int kq   = (lane >> 4) * 4;      // word offset: (lane>>4)*8 shorts

    const unsigned* base = XnT + ((size_t)b << 16);          // b*128*512 words
    const unsigned* Ap  = base + ((size_t)(band * 16 + l15) << 9) + kq;
    const unsigned* B0p = base + ((size_t)(w * 32 + l15) << 9) + kq;
    const unsigned* B1p = base + ((size_t)(w * 32 + 16 + l15) << 9) + kq;

    floatx4 acc0 = {0.f, 0.f, 0.f, 0.f}, acc1 = {0.f, 0.f, 0.f, 0.f};
#pragma unroll 8
    for (int kk = 0; kk < 32; ++kk) {      // K = 32 steps of 32 shorts
        short8 a  = *(const short8*)(Ap  + kk * 16);
        short8 b0 = *(const short8*)(B0p + kk * 16);
        short8 b1 = *(const short8*)(B1p + kk * 16);
        acc0 = __builtin_amdgcn_mfma_f32_16x16x32_bf16(a, b0, acc0, 0, 0, 0);
        acc1 = __builtin_amdgcn_mfma_f32_16x16x32_bf16(a, b1, acc1, 0, 0, 0);
    }

    float s = acc0[0] * acc0[0] + acc0[1] * acc0[1] +
              acc0[2] * acc0[2] + acc0[3] * acc0[3] +
              acc1[0] * acc1[0] + acc1[1] * acc1[1] +
              acc1[2] * acc1[2] + acc1[3] * acc1[3];

    // band-0 wgs fold the v-term: -2 * sum_f (sum over 8 kA slices)^2
    if (band == 0 && t < DIM) {
        float vv = 0.0f;
#pragma unroll
        for (int sblk = 0; sblk < 8; ++sblk) {
            const float* p = vpartA + (size_t)(sblk * 64 + b) * 256;
            vv += p[t] + p[t + 128];
        }
        s -= 2.0f * vv * vv;
    }

#pragma unroll
    for (int m = 1; m < 64; m <<= 1) s += __shfl_xor(s, m);
    __shared__ float wq[4];
    if (lane == 0) wq[w] = s;
    __syncthreads();
    if (t == 0) res[wg] = wq[0] + wq[1] + wq[2] + wq[3];
}

// ---- kF: out = sum(res[0..511]) / (B*S^2) + 1 ----
__global__ __launch_bounds__(256)
void kF_final(const float* __restrict__ res, float* __restrict__ out) {
    const int t = threadIdx.x;
    float s = res[t] + res[t + 256];
#pragma unroll
    for (int m = 1; m < 64; m <<= 1) s += __shfl_xor(s, m);
    __shared__ float wq[4];
    if ((t & 63) == 0) wq[t >> 6] = s;
    __syncthreads();
    if (t == 0)
        out[0] = (wq[0] + wq[1] + wq[2] + wq[3]) * (1.0f / 67108864.0f) + 1.0f;
}

extern "C" void kernel_launch(void* const* d_in, const int* in_sizes, int n_in,
                              void* d_out, int out_size, void* d_ws, size_t ws_size,
                              hipStream_t stream) {
    const float* X = (const float*)d_in[0];
    char* ws = (char*)d_ws;                 // needs ~17.3 MB
    unsigned* XnT  = (unsigned*)(ws + XNT_B);
    float* vpartA  = (float*)(ws + VP_B);
    float* res     = (float*)(ws + RES_B);

    kA_norm_t<<<512, 256, 0, stream>>>(X, XnT, vpartA);
    kB_gram<<<512, 256, 0, stream>>>(XnT, vpartA, res);
    kF_final<<<1, 256, 0, stream>>>(res, (float*)d_out);
}

// Round 9
// 86.854 us; speedup vs baseline: 1.5034x; 1.1861x over previous
//
#include <hip/hip_runtime.h>
#include <hip/hip_bf16.h>

// Problem: X[64][1024][128] fp32. out = mean_{b,s,t} (cos(x_bs, x_bt) - 1)^2
// Identity: sum_{s,t}(S_st-1)^2 = ||G||_F^2 - 2*||v||^2 + S^2,
//   G = Xn^T Xn (128x128 per batch), v = sum_s xn_s. 2.15 GFLOP, no SxS.
//
// ROUND-9: rounds 7/8 showed kA+kB ~= 45 us vs ~12 us model. Source-level
// suspect: 16 B/lane stores (kA) and loads (kB) at 2 KB inter-lane stride =
// 64 distinct cachelines per wave-instruction. Fix: fragment-tiled XnT
// layout [b][rb=f/16][kk=s/32][kqi=(s/8)%4][l15=f%16][8 shorts] -> each kB
// fragment load is one lane-linear 1 KB transaction; kA stores become 4x256B
// contiguous groups. Per-lane fragment CONTENTS identical to round 8
// (validated absmax 0.0) -- only addresses changed.

#define BATCH 64
#define SEQ   1024
#define DIM   128

typedef short short8  __attribute__((ext_vector_type(8)));
typedef float floatx4 __attribute__((ext_vector_type(4)));

__device__ __forceinline__ unsigned bf16rne(float x) {
    unsigned u = __builtin_bit_cast(unsigned, x);
    return (u + 0x7FFFu + ((u >> 16) & 1u)) >> 16;
}

// ws layout (bytes): [0,16MB) XnT tiled bf16; [16MB,+512KB) vpartA[512][256];
//   then res[512].
#define XNT_B  0
#define VP_B   16777216
#define RES_B  (VP_B + 512 * 256 * 4)

// tiled block (words): base = ((b*8 + rb)*32 + kk) << 8, 256 words = 1 KB;
// within: word = (kqi*16 + l15)*4 + w.

// ---- kA: wg = sblk*64 + b (XCD b%8). Normalize 128 rows, LDS-transpose,
//      store tiled bf16 XnT + v partials. ----
__global__ __launch_bounds__(256, 2)
void kA_norm_t(const float* __restrict__ X, unsigned* __restrict__ XnT,
               float* __restrict__ vpartA) {
    __shared__ __align__(16) float lds[64][132];   // 33.8 KB, +4 pad
    const int t    = threadIdx.x;
    const int wg   = blockIdx.x;           // sblk*64 + b
    const int b    = wg & 63, sblk = wg >> 6;
    const int sl   = t >> 2, q = t & 3;    // staging: 4 thr/row
    const int f    = t & 127, sh = t >> 7; // transpose: feature f, s-half
    const int rb   = f >> 4, l15 = f & 15;

    float4 g[2][8];
#pragma unroll
    for (int c = 0; c < 2; ++c) {
        const float4* rp = (const float4*)(
            X + ((size_t)(b * SEQ + sblk * 128 + c * 64 + sl) * DIM + q * 32));
#pragma unroll
        for (int k = 0; k < 8; ++k) g[c][k] = rp[k];
    }

    float vacc = 0.0f;
#pragma unroll
    for (int c = 0; c < 2; ++c) {
        float ssq = 0.0f;
#pragma unroll
        for (int k = 0; k < 8; ++k)
            ssq += g[c][k].x * g[c][k].x + g[c][k].y * g[c][k].y +
                   g[c][k].z * g[c][k].z + g[c][k].w * g[c][k].w;
        ssq += __shfl_xor(ssq, 1);
        ssq += __shfl_xor(ssq, 2);
        const float inv = rsqrtf(fmaxf(ssq, 1e-24f));

        if (c) __syncthreads();
#pragma unroll
        for (int k = 0; k < 8; ++k) {
            float4 n;
            n.x = g[c][k].x * inv; n.y = g[c][k].y * inv;
            n.z = g[c][k].z * inv; n.w = g[c][k].w * inv;
            *(float4*)&lds[sl][q * 32 + k * 4] = n;
        }
        __syncthreads();

        // transposed read: column f, s = s0..s0+31, s0 = sblk*128+c*64+sh*32
        float v[32];
#pragma unroll
        for (int j = 0; j < 32; ++j) {
            v[j] = lds[sh * 32 + j][f];
            vacc += v[j];
        }
        unsigned pk[16];
#pragma unroll
        for (int p = 0; p < 16; ++p)
            pk[p] = bf16rne(v[2 * p]) | (bf16rne(v[2 * p + 1]) << 16);

        // tiled store: kk = s0>>5; thread's uint4 k covers kqi=k
        const int kk = sblk * 4 + c * 2 + sh;
        uint4* op = (uint4*)(XnT + (((size_t)((b * 8 + rb) * 32 + kk)) << 8));
#pragma unroll
        for (int k = 0; k < 4; ++k)
            op[k * 16 + l15] = make_uint4(pk[4 * k], pk[4 * k + 1],
                                          pk[4 * k + 2], pk[4 * k + 3]);
    }
    vpartA[(size_t)wg * 256 + t] = vacc;
}

// ---- kB: wg = band*64 + b (XCD b%8). Full K=1024 Gram strip; every
//      fragment load = one contiguous 1 KB block (lane-linear). ----
__global__ __launch_bounds__(256, 2)
void kB_gram(const unsigned* __restrict__ XnT, const float* __restrict__ vpartA,
             float* __restrict__ res) {
    const int t    = threadIdx.x;
    const int wg   = blockIdx.x;
    const int b    = wg & 63, band = wg >> 6;
    const int lane = t & 63, w = t >> 6;

    // lane-linear: lane covers (l15 = lane&15, kqi = lane>>4) -> offset lane*4
    const unsigned* Ab  = XnT + (((size_t)((b * 8 + band) * 32)) << 8) + lane * 4;
    const unsigned* B0b = XnT + (((size_t)((b * 8 + 2 * w) * 32)) << 8) + lane * 4;
    const unsigned* B1b = XnT + (((size_t)((b * 8 + 2 * w + 1) * 32)) << 8) + lane * 4;

    floatx4 acc0 = {0.f, 0.f, 0.f, 0.f}, acc1 = {0.f, 0.f, 0.f, 0.f};
#pragma unroll 8
    for (int kk = 0; kk < 32; ++kk) {
        short8 a  = *(const short8*)(Ab  + (kk << 8));
        short8 b0 = *(const short8*)(B0b + (kk << 8));
        short8 b1 = *(const short8*)(B1b + (kk << 8));
        acc0 = __builtin_amdgcn_mfma_f32_16x16x32_bf16(a, b0, acc0, 0, 0, 0);
        acc1 = __builtin_amdgcn_mfma_f32_16x16x32_bf16(a, b1, acc1, 0, 0, 0);
    }

    float s = acc0[0] * acc0[0] + acc0[1] * acc0[1] +
              acc0[2] * acc0[2] + acc0[3] * acc0[3] +
              acc1[0] * acc1[0] + acc1[1] * acc1[1] +
              acc1[2] * acc1[2] + acc1[3] * acc1[3];

    // band-0 wgs fold -2*||v_b||^2
    if (band == 0 && t < DIM) {
        float vv = 0.0f;
#pragma unroll
        for (int sblk = 0; sblk < 8; ++sblk) {
            const float* p = vpartA + (size_t)(sblk * 64 + b) * 256;
            vv += p[t] + p[t + 128];
        }
        s -= 2.0f * vv * vv;
    }

#pragma unroll
    for (int m = 1; m < 64; m <<= 1) s += __shfl_xor(s, m);
    __shared__ float wq[4];
    if (lane == 0) wq[w] = s;
    __syncthreads();
    if (t == 0) res[wg] = wq[0] + wq[1] + wq[2] + wq[3];
}

// ---- kF: out = sum(res[0..511]) / (B*S^2) + 1 ----
__global__ __launch_bounds__(256)
void kF_final(const float* __restrict__ res, float* __restrict__ out) {
    const int t = threadIdx.x;
    float s = res[t] + res[t + 256];
#pragma unroll
    for (int m = 1; m < 64; m <<= 1) s += __shfl_xor(s, m);
    __shared__ float wq[4];
    if ((t & 63) == 0) wq[t >> 6] = s;
    __syncthreads();
    if (t == 0)
        out[0] = (wq[0] + wq[1] + wq[2] + wq[3]) * (1.0f / 67108864.0f) + 1.0f;
}

extern "C" void kernel_launch(void* const* d_in, const int* in_sizes, int n_in,
                              void* d_out, int out_size, void* d_ws, size_t ws_size,
                              hipStream_t stream) {
    const float* X = (const float*)d_in[0];
    char* ws = (char*)d_ws;                 // needs ~17.3 MB
    unsigned* XnT  = (unsigned*)(ws + XNT_B);
    float* vpartA  = (float*)(ws + VP_B);
    float* res     = (float*)(ws + RES_B);

    kA_norm_t<<<512, 256, 0, stream>>>(X, XnT, vpartA);
    kB_gram<<<512, 256, 0, stream>>>(XnT, vpartA, res);
    kF_final<<<1, 256, 0, stream>>>(res, (float*)d_out);
}